// Round 3
// baseline (148.289 us; speedup 1.0000x reference)
//
#include <hip/hip_runtime.h>
#include <math.h>

#define NPTS 1024
#define HID 64

// ---------------------------------------------------------------------------
// Kernel 1: one block per row i. Compute all 1024 distances (exact fp32
// arithmetic matching the numpy/JAX reference on the comparison path),
// density counts per scale, and the 26 smallest distances -> kNN entropies.
// ---------------------------------------------------------------------------
__global__ __launch_bounds__(256) void k_rows(const float* __restrict__ pts,
                                              float* __restrict__ density,
                                              float* __restrict__ ent) {
    __shared__ float sx[NPTS], sy[NPTS], sz[NPTS];
    __shared__ float dist_s[NPTS];
    __shared__ float rv[256];
    __shared__ int   ri[256];
    __shared__ int   cnt[3];
    __shared__ float knn[26];

    const int i = blockIdx.x;
    const int t = threadIdx.x;

    for (int j = t; j < NPTS; j += 256) {
        sx[j] = pts[j * 3 + 0];
        sy[j] = pts[j * 3 + 1];
        sz[j] = pts[j * 3 + 2];
    }
    if (t < 3) cnt[t] = 0;
    __syncthreads();

    const float px = sx[i], py = sy[i], pz = sz[i];
    int c0 = 0, c1 = 0, c2 = 0;
    for (int j = t; j < NPTS; j += 256) {
        // exact rounding, no fma contraction: ((dx*dx + dy*dy) + dz*dz)
        float dx = __fsub_rn(px, sx[j]);
        float dy = __fsub_rn(py, sy[j]);
        float dz = __fsub_rn(pz, sz[j]);
        float d2 = __fadd_rn(__fadd_rn(__fmul_rn(dx, dx), __fmul_rn(dy, dy)),
                             __fmul_rn(dz, dz));
        float d = __fsqrt_rn(d2 > 0.0f ? d2 : 1e-12f);  // _safe_sqrt
        dist_s[j] = d;
        c0 += (d < 0.1f);
        c1 += (d < 0.2f);
        c2 += (d < 0.4f);
    }
    atomicAdd(&cnt[0], c0);
    atomicAdd(&cnt[1], c1);
    atomicAdd(&cnt[2], c2);
    __syncthreads();

    if (t < 3) {
        const float scl[3] = {0.1f, 0.2f, 0.4f};
        float s  = scl[t];
        float s3 = __fmul_rn(__fmul_rn(s, s), s);
        float vol = __fmul_rn((float)(4.0 / 3.0 * M_PI), s3);
        density[i * 3 + t] = (float)cnt[t] / vol;
    }

    // Extract the 26 smallest distances (rank 0 = self).
    for (int it = 0; it < 26; ++it) {
        float mv = 1e30f;
        int   mi = 0;
        for (int j = t; j < NPTS; j += 256) {
            float v = dist_s[j];
            if (v < mv) { mv = v; mi = j; }
        }
        rv[t] = mv; ri[t] = mi;
        __syncthreads();
        for (int off = 128; off > 0; off >>= 1) {
            if (t < off && rv[t + off] < rv[t]) {
                rv[t] = rv[t + off];
                ri[t] = ri[t + off];
            }
            __syncthreads();
        }
        if (t == 0) {
            knn[it] = rv[0];
            dist_s[ri[0]] = 1e30f;  // remove from candidate set
        }
        __syncthreads();
    }

    if (t == 0) {
        const int kv[3] = {5, 10, 25};
        for (int q = 0; q < 3; ++q) {
            int k = kv[q];
            double ssum = 0.0;
            for (int r = 1; r <= k; ++r) ssum += (double)knn[r];
            double e = 0.0;
            for (int r = 1; r <= k; ++r) {
                double p = (double)knn[r] / ssum;
                e -= p * log(p + 1e-10);
            }
            ent[i * 3 + q] = (float)e;
        }
    }
}

// ---------------------------------------------------------------------------
// Kernel 2: fp64 reduction of density -> S1[s], S2[s] (for gradient expansion)
// ---------------------------------------------------------------------------
__global__ __launch_bounds__(256) void k_sums(const float* __restrict__ density,
                                              double* __restrict__ sums) {
    __shared__ double s1[3][256];
    __shared__ double s2[3][256];
    const int t = threadIdx.x;
    double a[3] = {0.0, 0.0, 0.0};
    double b[3] = {0.0, 0.0, 0.0};
    for (int j = t; j < NPTS; j += 256) {
        for (int s = 0; s < 3; ++s) {
            double d = (double)density[j * 3 + s];
            a[s] += d;
            b[s] += d * d;
        }
    }
    for (int s = 0; s < 3; ++s) { s1[s][t] = a[s]; s2[s][t] = b[s]; }
    __syncthreads();
    for (int off = 128; off > 0; off >>= 1) {
        if (t < off) {
            for (int s = 0; s < 3; ++s) {
                s1[s][t] += s1[s][t + off];
                s2[s][t] += s2[s][t + off];
            }
        }
        __syncthreads();
    }
    if (t < 3) {
        sums[t]     = s1[t][0];
        sums[3 + t] = s2[t][0];
    }
}

// ---------------------------------------------------------------------------
// Kernel 3: per-row embedding. One wave (64 threads) per row; thread = hidden
// unit. gradient via expansion, l2norms, two matvecs, sum -> s[1024][64].
// ---------------------------------------------------------------------------
__global__ __launch_bounds__(64) void k_embed(const float* __restrict__ density,
                                              const float* __restrict__ ent,
                                              const double* __restrict__ sums,
                                              const float* __restrict__ Wm,
                                              const float* __restrict__ bm,
                                              const float* __restrict__ Wl,
                                              const float* __restrict__ bl,
                                              float* __restrict__ svec) {
    const int i = blockIdx.x;
    const int h = threadIdx.x;

    // mdve = l2norm([density(3), gradient(3)])
    float m[6];
    double nrm6 = 0.0;
    for (int s = 0; s < 3; ++s) {
        float d = density[i * 3 + s];
        m[s] = d;
        double dd = (double)d;
        double g2 = 1024.0 * dd * dd - 2.0 * dd * sums[s] + sums[3 + s];
        m[3 + s] = (float)sqrt(g2 > 0.0 ? g2 : 1e-12);
    }
    for (int s = 0; s < 6; ++s) nrm6 += (double)m[s] * (double)m[s];
    float inv6 = 1.0f / fmaxf((float)sqrt(nrm6), 1e-12f);
    for (int s = 0; s < 6; ++s) m[s] *= inv6;

    // lgee = l2norm(entropies(3))
    float l[3];
    double nrm3 = 0.0;
    for (int s = 0; s < 3; ++s) {
        l[s] = ent[i * 3 + s];
        nrm3 += (double)l[s] * (double)l[s];
    }
    float inv3 = 1.0f / fmaxf((float)sqrt(nrm3), 1e-12f);
    for (int s = 0; s < 3; ++s) l[s] *= inv3;

    // y = mdve @ Wm + bm ; l2norm over the 64 hidden units (one wave)
    float y = bm[h];
    for (int s = 0; s < 6; ++s) y += m[s] * Wm[s * HID + h];
    float yy = y * y;
    for (int off = 32; off > 0; off >>= 1) yy += __shfl_xor(yy, off);
    y *= 1.0f / fmaxf(sqrtf(yy), 1e-12f);

    // z = lgee @ Wl + bl ; l2norm
    float z = bl[h];
    for (int s = 0; s < 3; ++s) z += l[s] * Wl[s * HID + h];
    float zz = z * z;
    for (int off = 32; off > 0; off >>= 1) zz += __shfl_xor(zz, off);
    z *= 1.0f / fmaxf(sqrtf(zz), 1e-12f);

    svec[i * HID + h] = y + z;
}

// ---------------------------------------------------------------------------
// Kernel 4: broadcast s (256 KB) over the i dimension -> 256 MiB output.
// out[((i*N)+j)*64+h] = s[j*64+h]  ==  out tiles s N times.
// ---------------------------------------------------------------------------
__global__ __launch_bounds__(256) void k_bcast(const float4* __restrict__ s4,
                                               float4* __restrict__ out) {
    const int total = (NPTS * NPTS * HID) / 4;       // 16,777,216 float4
    const int mask  = (NPTS * HID) / 4 - 1;          // 16383
    int idx = blockIdx.x * 256 + threadIdx.x;
    const int stride = gridDim.x * 256;
    for (; idx < total; idx += stride) {
        out[idx] = s4[idx & mask];
    }
}

extern "C" void kernel_launch(void* const* d_in, const int* in_sizes, int n_in,
                              void* d_out, int out_size, void* d_ws, size_t ws_size,
                              hipStream_t stream) {
    const float* pts = (const float*)d_in[0];
    // d_in[1], d_in[2] (W_rtdie, b_rtdie) do not affect the output.
    const float* Wm = (const float*)d_in[3];
    const float* bm = (const float*)d_in[4];
    const float* Wl = (const float*)d_in[5];
    const float* bl = (const float*)d_in[6];

    char* ws = (char*)d_ws;
    float*  density = (float*)(ws);            // 1024*3*4   = 12288 B
    float*  entv    = (float*)(ws + 12288);    // 1024*3*4   = 12288 B
    double* sums    = (double*)(ws + 24576);   // 6*8        = 48 B
    float*  svec    = (float*)(ws + 32768);    // 1024*64*4  = 262144 B

    float* out = (float*)d_out;

    hipLaunchKernelGGL(k_rows, dim3(NPTS), dim3(256), 0, stream, pts, density, entv);
    hipLaunchKernelGGL(k_sums, dim3(1), dim3(256), 0, stream, density, sums);
    hipLaunchKernelGGL(k_embed, dim3(NPTS), dim3(HID), 0, stream,
                       density, entv, sums, Wm, bm, Wl, bl, svec);
    hipLaunchKernelGGL(k_bcast, dim3(2048), dim3(256), 0, stream,
                       (const float4*)svec, (float4*)out);
}

// Round 4
// 93.949 us; speedup vs baseline: 1.5784x; 1.5784x over previous
//
#include <hip/hip_runtime.h>
#include <math.h>

#define NPTS 1024
#define HID 64

// ---------------------------------------------------------------------------
// Kernel 1: one block (256 thr = 4 waves) per row i.
// Distances in exact fp32 (matches numpy rounding on the density-count path),
// density counts, and wave-parallel extraction of the 26 smallest distances
// -> kNN entropies. 3 block barriers total (was ~208).
// ---------------------------------------------------------------------------
__global__ __launch_bounds__(256) void k_rows(const float* __restrict__ pts,
                                              float* __restrict__ density,
                                              float* __restrict__ ent) {
    __shared__ float wk[4 * 26];   // per-wave top-26
    __shared__ float knn[26];      // merged top-26
    __shared__ int   cnt[3];

    const int i    = blockIdx.x;
    const int t    = threadIdx.x;
    const int lane = t & 63;
    const int wid  = t >> 6;

    if (t < 3) cnt[t] = 0;
    __syncthreads();   // cnt init visible before atomics

    const float px = pts[i * 3 + 0];
    const float py = pts[i * 3 + 1];
    const float pz = pts[i * 3 + 2];

    // 4 distances per thread, kept in registers (static indices only).
    float v[4];
    int c0 = 0, c1 = 0, c2 = 0;
    #pragma unroll
    for (int q = 0; q < 4; ++q) {
        const int j = t + q * 256;
        // exact rounding, no fma contraction: ((dx*dx + dy*dy) + dz*dz)
        float dx = __fsub_rn(px, pts[j * 3 + 0]);
        float dy = __fsub_rn(py, pts[j * 3 + 1]);
        float dz = __fsub_rn(pz, pts[j * 3 + 2]);
        float d2 = __fadd_rn(__fadd_rn(__fmul_rn(dx, dx), __fmul_rn(dy, dy)),
                             __fmul_rn(dz, dz));
        float d = __fsqrt_rn(d2 > 0.0f ? d2 : 1e-12f);  // _safe_sqrt
        v[q] = d;
        c0 += (d < 0.1f);
        c1 += (d < 0.2f);
        c2 += (d < 0.4f);
    }

    // Pack the three counts (<=4 each per lane, <=256 per wave) into one int.
    int packed = c0 | (c1 << 10) | (c2 << 20);
    #pragma unroll
    for (int off = 32; off > 0; off >>= 1) packed += __shfl_xor(packed, off);
    if (lane == 0) {
        atomicAdd(&cnt[0], packed & 1023);
        atomicAdd(&cnt[1], (packed >> 10) & 1023);
        atomicAdd(&cnt[2], packed >> 20);
    }

    // Per-wave extraction of the 26 smallest (barrier-free, registers only).
    for (int it = 0; it < 26; ++it) {
        float lm = v[0]; int li = 0;
        if (v[1] < lm) { lm = v[1]; li = 1; }
        if (v[2] < lm) { lm = v[2]; li = 2; }
        if (v[3] < lm) { lm = v[3]; li = 3; }
        float m = lm; int idx = (lane << 2) | li;
        #pragma unroll
        for (int off = 32; off > 0; off >>= 1) {
            float om = __shfl_xor(m, off);
            int   oi = __shfl_xor(idx, off);
            if (om < m || (om == m && oi < idx)) { m = om; idx = oi; }
        }
        // exactly one owner invalidates (lexicographic tie-break => unique idx)
        const int inv = ((idx >> 2) == lane) ? (idx & 3) : -1;
        if (inv == 0) v[0] = 1e30f;
        if (inv == 1) v[1] = 1e30f;
        if (inv == 2) v[2] = 1e30f;
        if (inv == 3) v[3] = 1e30f;
        if (lane == 0) wk[wid * 26 + it] = m;
    }
    __syncthreads();

    if (t < 3) {
        const float scl[3] = {0.1f, 0.2f, 0.4f};
        float s   = scl[t];
        float s3  = __fmul_rn(__fmul_rn(s, s), s);
        float vol = __fmul_rn((float)(4.0 / 3.0 * M_PI), s3);
        density[i * 3 + t] = (float)cnt[t] / vol;
    }

    // Wave 0: merge 4x26 candidates -> global top-26, then entropies.
    if (wid == 0) {
        float e0 = (lane < 104) ? wk[lane] : 1e30f;
        float e1 = (lane + 64 < 104) ? wk[lane + 64] : 1e30f;
        for (int it = 0; it < 26; ++it) {
            float lm; int li;
            if (e0 <= e1) { lm = e0; li = 0; } else { lm = e1; li = 1; }
            float m = lm; int idx = (lane << 1) | li;
            #pragma unroll
            for (int off = 32; off > 0; off >>= 1) {
                float om = __shfl_xor(m, off);
                int   oi = __shfl_xor(idx, off);
                if (om < m || (om == m && oi < idx)) { m = om; idx = oi; }
            }
            if ((idx >> 1) == lane) { if (idx & 1) e1 = 1e30f; else e0 = 1e30f; }
            if (lane == 0) knn[it] = m;   // rank it (0 = self)
        }
        // entropies: lanes 1..k hold knn[lane] (self at rank 0 dropped)
        float nd = (lane >= 1 && lane <= 25) ? knn[lane] : 0.0f;
        const int kv[3] = {5, 10, 25};
        #pragma unroll
        for (int q = 0; q < 3; ++q) {
            const int k = kv[q];
            float x = (lane >= 1 && lane <= k) ? nd : 0.0f;
            float S = x;
            #pragma unroll
            for (int off = 32; off > 0; off >>= 1) S += __shfl_xor(S, off);
            float p = x / S;
            float term = (lane >= 1 && lane <= k) ? -p * logf(p + 1e-10f) : 0.0f;
            float E = term;
            #pragma unroll
            for (int off = 32; off > 0; off >>= 1) E += __shfl_xor(E, off);
            if (lane == 0) ent[i * 3 + q] = E;
        }
    }
}

// ---------------------------------------------------------------------------
// Kernel 2: fp64 reduction of density -> S1[s], S2[s] (for gradient expansion)
// ---------------------------------------------------------------------------
__global__ __launch_bounds__(256) void k_sums(const float* __restrict__ density,
                                              double* __restrict__ sums) {
    __shared__ double s1[3][256];
    __shared__ double s2[3][256];
    const int t = threadIdx.x;
    double a[3] = {0.0, 0.0, 0.0};
    double b[3] = {0.0, 0.0, 0.0};
    for (int j = t; j < NPTS; j += 256) {
        for (int s = 0; s < 3; ++s) {
            double d = (double)density[j * 3 + s];
            a[s] += d;
            b[s] += d * d;
        }
    }
    for (int s = 0; s < 3; ++s) { s1[s][t] = a[s]; s2[s][t] = b[s]; }
    __syncthreads();
    for (int off = 128; off > 0; off >>= 1) {
        if (t < off) {
            for (int s = 0; s < 3; ++s) {
                s1[s][t] += s1[s][t + off];
                s2[s][t] += s2[s][t + off];
            }
        }
        __syncthreads();
    }
    if (t < 3) {
        sums[t]     = s1[t][0];
        sums[3 + t] = s2[t][0];
    }
}

// ---------------------------------------------------------------------------
// Kernel 3: per-row embedding. One wave (64 threads) per row; thread = hidden
// unit. gradient via expansion, l2norms, two matvecs, sum -> s[1024][64].
// ---------------------------------------------------------------------------
__global__ __launch_bounds__(64) void k_embed(const float* __restrict__ density,
                                              const float* __restrict__ ent,
                                              const double* __restrict__ sums,
                                              const float* __restrict__ Wm,
                                              const float* __restrict__ bm,
                                              const float* __restrict__ Wl,
                                              const float* __restrict__ bl,
                                              float* __restrict__ svec) {
    const int i = blockIdx.x;
    const int h = threadIdx.x;

    // mdve = l2norm([density(3), gradient(3)])
    float m[6];
    double nrm6 = 0.0;
    for (int s = 0; s < 3; ++s) {
        float d = density[i * 3 + s];
        m[s] = d;
        double dd = (double)d;
        double g2 = 1024.0 * dd * dd - 2.0 * dd * sums[s] + sums[3 + s];
        m[3 + s] = (float)sqrt(g2 > 0.0 ? g2 : 1e-12);
    }
    for (int s = 0; s < 6; ++s) nrm6 += (double)m[s] * (double)m[s];
    float inv6 = 1.0f / fmaxf((float)sqrt(nrm6), 1e-12f);
    for (int s = 0; s < 6; ++s) m[s] *= inv6;

    // lgee = l2norm(entropies(3))
    float l[3];
    double nrm3 = 0.0;
    for (int s = 0; s < 3; ++s) {
        l[s] = ent[i * 3 + s];
        nrm3 += (double)l[s] * (double)l[s];
    }
    float inv3 = 1.0f / fmaxf((float)sqrt(nrm3), 1e-12f);
    for (int s = 0; s < 3; ++s) l[s] *= inv3;

    // y = mdve @ Wm + bm ; l2norm over the 64 hidden units (one wave)
    float y = bm[h];
    for (int s = 0; s < 6; ++s) y += m[s] * Wm[s * HID + h];
    float yy = y * y;
    for (int off = 32; off > 0; off >>= 1) yy += __shfl_xor(yy, off);
    y *= 1.0f / fmaxf(sqrtf(yy), 1e-12f);

    // z = lgee @ Wl + bl ; l2norm
    float z = bl[h];
    for (int s = 0; s < 3; ++s) z += l[s] * Wl[s * HID + h];
    float zz = z * z;
    for (int off = 32; off > 0; off >>= 1) zz += __shfl_xor(zz, off);
    z *= 1.0f / fmaxf(sqrtf(zz), 1e-12f);

    svec[i * HID + h] = y + z;
}

// ---------------------------------------------------------------------------
// Kernel 4: broadcast s (256 KB) over the i dimension -> 256 MiB output.
// out[((i*N)+j)*64+h] = s[j*64+h]  ==  out tiles s N times.
// ---------------------------------------------------------------------------
__global__ __launch_bounds__(256) void k_bcast(const float4* __restrict__ s4,
                                               float4* __restrict__ out) {
    const int total = (NPTS * NPTS * HID) / 4;       // 16,777,216 float4
    const int mask  = (NPTS * HID) / 4 - 1;          // 16383
    int idx = blockIdx.x * 256 + threadIdx.x;
    const int stride = gridDim.x * 256;
    for (; idx < total; idx += stride) {
        out[idx] = s4[idx & mask];
    }
}

extern "C" void kernel_launch(void* const* d_in, const int* in_sizes, int n_in,
                              void* d_out, int out_size, void* d_ws, size_t ws_size,
                              hipStream_t stream) {
    const float* pts = (const float*)d_in[0];
    // d_in[1], d_in[2] (W_rtdie, b_rtdie) do not affect the output.
    const float* Wm = (const float*)d_in[3];
    const float* bm = (const float*)d_in[4];
    const float* Wl = (const float*)d_in[5];
    const float* bl = (const float*)d_in[6];

    char* ws = (char*)d_ws;
    float*  density = (float*)(ws);            // 1024*3*4   = 12288 B
    float*  entv    = (float*)(ws + 12288);    // 1024*3*4   = 12288 B
    double* sums    = (double*)(ws + 24576);   // 6*8        = 48 B
    float*  svec    = (float*)(ws + 32768);    // 1024*64*4  = 262144 B

    float* out = (float*)d_out;

    hipLaunchKernelGGL(k_rows, dim3(NPTS), dim3(256), 0, stream, pts, density, entv);
    hipLaunchKernelGGL(k_sums, dim3(1), dim3(256), 0, stream, density, sums);
    hipLaunchKernelGGL(k_embed, dim3(NPTS), dim3(HID), 0, stream,
                       density, entv, sums, Wm, bm, Wl, bl, svec);
    hipLaunchKernelGGL(k_bcast, dim3(2048), dim3(256), 0, stream,
                       (const float4*)svec, (float4*)out);
}